// Round 14
// baseline (1731.929 us; speedup 1.0000x reference)
//
#include <hip/hip_runtime.h>

// ============================================================================
// UnidirecLSTMLayerWithDropoutBefore: dropout(Threefry) -> x@Wi GEMM -> LSTM
// B=64, T=2048, D=256, H=256, gates (i,f,g,o), dropout 0.1, key 42.
//
// R13 = R12 + dropout moved INTO the fused kernel as a producer role:
//   blocks [0,32)      lstm   (R6 body; waits flags[ch] per 128-t chunk)
//   blocks [32,8224)   dropout (x -> xd, t-chunk-major; signals flags2[tc])
//   blocks [8224,16416) gemm  (waits flags2[tc]; xd@Wi -> xp; signals flags[tc])
// Dropout precedes gemm in dispatch order -> no CU-starvation deadlock.
// Critical path to lstm start: drop-chunk0 (~2us) + gemm-chunk0 (~23us),
// vs R12's serial k_dropout (~35us) + ramp (~25us).
// R11 lesson: dropout fused into gemm STAGING recomputes Threefry x8 -> VALU-
// bound; here each element computed ONCE (pure relocation of k_dropout).
// Handshake (validated R10): sc0sc1 write-through stores + vmcnt(0) + one
// relaxed device atomicAdd; consumers acquire-poll (buffer_inv).
// lstm body = R6 (standalone 1347us; 1024cyc/SIMD MFMA floor + ~300 handoff).
//
// ws layout (bytes):
//   [0, 64MiB)            Xd   bf16 [131072][256]
//   [64MiB, 320MiB)       Xp   bf16 [t*64+b][u*4+g], PRE-SCALED by gate:
//                              i,o: *L   f: *-L   g: *2L   (L = log2e)
//   [335544320, +512KiB)  WiT  bf16 [1024][256]
//   [336068608, +4KiB)    dq   f32 [1024]  (s/127^2 * gate-scale)
//   [336072704, +4KiB)    qs   f32 [1024]  (127/s)
//   [336076800, +256KiB)  Wq   i8 packed MFMA-B frags [ntg][kt][lane][16]
//   [336338944, +128B)    flags u32[16] (gemm->lstm) | flags2 u32[16]
// Output f32: c_last[16384] | h_last[16384] | outputs[64*2048*256]
// ============================================================================

typedef __attribute__((ext_vector_type(8))) short short8;
typedef __attribute__((ext_vector_type(4))) float floatx4;
typedef __attribute__((ext_vector_type(4))) int int4v;
typedef __attribute__((ext_vector_type(4))) unsigned short us4;
typedef __attribute__((ext_vector_type(2))) unsigned int uint2v;
typedef __attribute__((ext_vector_type(4))) unsigned int uint4v;

#define LOG2E 1.44269504088896f

__device__ __forceinline__ unsigned short f2bf(float f) {
  unsigned int u = __float_as_uint(f);
  u = u + 0x7fffu + ((u >> 16) & 1u);   // RNE
  return (unsigned short)(u >> 16);
}
__device__ __forceinline__ float fexp2(float x) { return __builtin_amdgcn_exp2f(x); }
__device__ __forceinline__ float frcp(float x) { return __builtin_amdgcn_rcpf(x); }

// ---------------------------------------------------------------------------
// Threefry-2x32, key (0,42), partitionable scheme (verified bit-exact R0-R12)
// ---------------------------------------------------------------------------
__device__ __forceinline__ unsigned int tf_bits(unsigned int x0, unsigned int x1) {
  const unsigned int K0 = 0u, K1 = 42u;
  const unsigned int KX = K0 ^ K1 ^ 0x1BD11BDAu;
  x0 += K0; x1 += K1;
#define TF_R(r) { x0 += x1; x1 = (x1 << (r)) | (x1 >> (32 - (r))); x1 ^= x0; }
  TF_R(13) TF_R(15) TF_R(26) TF_R(6)   x0 += K1; x1 += KX + 1u;
  TF_R(17) TF_R(29) TF_R(16) TF_R(24)  x0 += KX; x1 += K0 + 2u;
  TF_R(13) TF_R(15) TF_R(26) TF_R(6)   x0 += K0; x1 += K1 + 3u;
  TF_R(17) TF_R(29) TF_R(16) TF_R(24)  x0 += K1; x1 += KX + 4u;
  TF_R(13) TF_R(15) TF_R(26) TF_R(6)   x0 += KX; x1 += K0 + 5u;
#undef TF_R
  return x0 ^ x1;
}

// ---------------------------------------------------------------------------
// k_prep: blocks [0,64) = colscale role; blocks [64,320) = pack_wi role.
// ---------------------------------------------------------------------------
__global__ __launch_bounds__(256) void k_prep(const float* __restrict__ wi,
                                              const float* __restrict__ wh,
                                              unsigned short* __restrict__ wit,
                                              float* __restrict__ dq,
                                              float* __restrict__ qs) {
  if (blockIdx.x < 64) {
    // colscale: per-column |max| -> dq (gate log2e scale baked) and qs
    __shared__ float red[256];
    const int t = threadIdx.x;
    const int n = blockIdx.x * 16 + (t & 15);
    const int kg = t >> 4;
    float m = 0.f;
#pragma unroll
    for (int i = 0; i < 16; ++i)
      m = fmaxf(m, fabsf(wh[(kg * 16 + i) * 1024 + n]));
    red[t] = m;
    __syncthreads();
    if (t < 16) {
      const int nn = blockIdx.x * 16 + t;
      float mm = red[t];
#pragma unroll
      for (int j = 1; j < 16; ++j) mm = fmaxf(mm, red[t + j * 16]);
      const float s = (mm > 0.f) ? mm : 1.f;
      const float gsc[4] = {LOG2E, -LOG2E, 2.f * LOG2E, LOG2E};
      dq[nn] = (s / 16129.0f) * gsc[nn >> 8];
      qs[nn] = 127.0f / s;
    }
    return;
  }
  // pack_wi: LDS-transpose, wit[n][k] = bf16(wi[k][n])
  __shared__ float tile[32][33];
  const int idx = (int)blockIdx.x - 64;      // 0..255
  const int k0 = (idx & 7) * 32, n0 = (idx >> 3) * 32;
  const int tx = threadIdx.x & 31, ty = threadIdx.x >> 5;
#pragma unroll
  for (int i = 0; i < 4; ++i)
    tile[ty + i * 8][tx] = wi[(k0 + ty + i * 8) * 1024 + n0 + tx];
  __syncthreads();
#pragma unroll
  for (int i = 0; i < 4; ++i)
    wit[(n0 + ty + i * 8) * 256 + k0 + tx] = f2bf(tile[tx][ty + i * 8]);
}

// Wq packed in i8 MFMA-B fragment order (16x16x64) — layout validated R1-R12.
__global__ __launch_bounds__(256) void k_pack_wh_i8(const float* __restrict__ wh,
                                                    const float* __restrict__ qs,
                                                    signed char* __restrict__ wq) {
  const int tid = blockIdx.x * 256 + threadIdx.x;
  const int j = tid & 15, l = (tid >> 4) & 63, kt = (tid >> 10) & 3, ntg = tid >> 12;
  const int k = kt * 64 + ((l >> 4) << 4) + j;
  const int n = ntg * 16 + (l & 15);
  float v = rintf(wh[k * 1024 + n] * qs[n]);
  v = fminf(fmaxf(v, -127.f), 127.f);
  wq[tid] = (signed char)(int)v;
}

// ---------------------------------------------------------------------------
// FUSED kernel: [0,32) lstm | [32,8224) dropout | [8224,16416) gemm.
// ---------------------------------------------------------------------------
__global__ __launch_bounds__(512, 2) void k_fused(
    const float* __restrict__ x, unsigned short* __restrict__ xd,
    const unsigned short* __restrict__ wit, const float* __restrict__ bias,
    unsigned short* __restrict__ xp, const signed char* __restrict__ wq,
    const float* __restrict__ dq, const int* __restrict__ lens,
    float* __restrict__ out, unsigned int* __restrict__ flags) {
  __shared__ __align__(16) unsigned short SH[45056];  // 88 KB -> 1 block/CU

  const int tid = threadIdx.x, lane = tid & 63;

  if (blockIdx.x >= 32 && blockIdx.x < 8224) {
    // ======================= DROPOUT role =======================
    // block db: tc = t-chunk, 16 xd rows (b-major within chunk), 512thr x 8 elems
    const int db = (int)blockIdx.x - 32;      // 0..8191
    const int tc = db >> 9, j = db & 511;
    const int rloc = tid >> 5;                // 0..15: row within block
    const int e0 = (tid & 31) * 8;            // elem within row
    const int gr = j * 16 + rloc;             // row within chunk 0..8191
    const int b = gr >> 7, i = gr & 127;
    const int m = b * 2048 + tc * 128 + i;    // xd row
    const unsigned int n0 = (unsigned int)m * 256u + (unsigned int)e0;

    const float4 x0 = *reinterpret_cast<const float4*>(x + (size_t)m * 256 + e0);
    const float4 x1 = *reinterpret_cast<const float4*>(x + (size_t)m * 256 + e0 + 4);
    const float xs[8] = {x0.x, x0.y, x0.z, x0.w, x1.x, x1.y, x1.z, x1.w};
    unsigned short r[8];
#pragma unroll
    for (int e = 0; e < 8; ++e) {
      const unsigned int bits = tf_bits(0u, n0 + (unsigned int)e);
      const float uu = __uint_as_float((bits >> 9) | 0x3f800000u) - 1.0f;
      const float vv = (uu < 0.9f) ? (xs[e] / 0.9f) : 0.0f;
      r[e] = f2bf(vv);
    }
    const uint4v ov = {(unsigned int)r[0] | ((unsigned int)r[1] << 16),
                       (unsigned int)r[2] | ((unsigned int)r[3] << 16),
                       (unsigned int)r[4] | ((unsigned int)r[5] << 16),
                       (unsigned int)r[6] | ((unsigned int)r[7] << 16)};
    unsigned short* p = xd + (size_t)m * 256 + e0;
    asm volatile("global_store_dwordx4 %0, %1, off sc0 sc1"
                 :: "v"(p), "v"(ov) : "memory");

    asm volatile("s_waitcnt vmcnt(0)" ::: "memory");
    __syncthreads();
    if (tid == 0) atomicAdd(&flags[16 + tc], 1u);
    return;
  }

  if (blockIdx.x >= 8224) {
    // ======================= GEMM role =======================
    const int gb = (int)blockIdx.x - 8224;
    const int tc = gb >> 9;
    const int rem = gb & 511;
    const int b = rem >> 3, y = rem & 7;
    const int m0 = b * 2048 + tc * 128;

    // wait for xd chunk tc (acquire -> inv stale lines)
    if (tid == 0) {
      while (__hip_atomic_load(&flags[16 + tc], __ATOMIC_ACQUIRE, __HIP_MEMORY_SCOPE_AGENT) < 512u)
        __builtin_amdgcn_s_sleep(2);
    }
    __syncthreads();

    const int wv = tid >> 6;
    const int wm = wv >> 2;
    const int wn = wv & 3;
    const int srow = tid >> 2, sseg = tid & 3;
    const unsigned short* gA = xd + (m0 + srow) * 256 + sseg * 8;
    const int nsrc = ((srow >> 5) << 8) + y * 32 + (srow & 31);
    const unsigned short* gB = wit + nsrc * 256 + sseg * 8;
    const int soff = srow * 40 + sseg * 8;

    const floatx4 zero4 = {0.f, 0.f, 0.f, 0.f};
    floatx4 acc[4][2];
#pragma unroll
    for (int i = 0; i < 4; ++i) { acc[i][0] = zero4; acc[i][1] = zero4; }

    short8 ra = *(const short8*)(gA);
    short8 rb = *(const short8*)(gB);
    *(short8*)&SH[soff] = ra;
    *(short8*)&SH[10240 + soff] = rb;
    __syncthreads();

    const int frow = (lane & 15) * 40 + ((lane >> 4) << 3);
#pragma unroll 1
    for (int kt = 0; kt < 8; ++kt) {
      const int boff = (kt & 1) * 5120;
      if (kt < 7) {
        ra = *(const short8*)(gA + (kt + 1) * 32);
        rb = *(const short8*)(gB + (kt + 1) * 32);
      }
      short8 af[4], bfv[2];
#pragma unroll
      for (int mt = 0; mt < 4; ++mt)
        af[mt] = *(const short8*)&SH[boff + (wm * 64 + mt * 16) * 40 + frow];
#pragma unroll
      for (int nt = 0; nt < 2; ++nt)
        bfv[nt] = *(const short8*)&SH[10240 + boff + (wn * 32 + nt * 16) * 40 + frow];
#pragma unroll
      for (int mt = 0; mt < 4; ++mt)
#pragma unroll
        for (int nt = 0; nt < 2; ++nt)
          acc[mt][nt] = __builtin_amdgcn_mfma_f32_16x16x32_bf16(af[mt], bfv[nt], acc[mt][nt], 0, 0, 0);
      if (kt < 7) {
        const int noff = boff ^ 5120;
        *(short8*)&SH[noff + soff] = ra;
        *(short8*)&SH[10240 + noff + soff] = rb;
      }
      __syncthreads();
    }

    const float gsc[4] = {LOG2E, -LOG2E, 2.f * LOG2E, LOG2E};
    const float gv = gsc[wn];
    float bv[2];
#pragma unroll
    for (int nt = 0; nt < 2; ++nt)
      bv[nt] = bias[wn * 256 + y * 32 + nt * 16 + (lane & 15)];

    __syncthreads();
#pragma unroll
    for (int mt = 0; mt < 4; ++mt)
#pragma unroll
      for (int nt = 0; nt < 2; ++nt) {
        const int jj = wn * 32 + nt * 16 + (lane & 15);
#pragma unroll
        for (int q = 0; q < 4; ++q) {
          const int row = wm * 64 + mt * 16 + ((lane >> 4) << 2) + q;
          SH[row * 132 + jj] = f2bf((acc[mt][nt][q] + bv[nt]) * gv);
        }
      }
    __syncthreads();

    // xp stores: sc0 sc1 write-through (no dirty L2 -> no fence needed).
#pragma unroll
    for (int k = 0; k < 8; ++k) {
      const int pi = k * 512 + tid;
      const int row = pi >> 5, u = pi & 31;
      us4 o = {SH[row * 132 + u], SH[row * 132 + 32 + u],
               SH[row * 132 + 64 + u], SH[row * 132 + 96 + u]};
      const int m = m0 + row;
      unsigned short* p = xp + ((size_t)(m & 2047) * 64 + (m >> 11)) * 1024 +
                          (size_t)(y * 32 + u) * 4;
      const uint2v ov = {(unsigned int)(unsigned short)o[0] | ((unsigned int)(unsigned short)o[1] << 16),
                         (unsigned int)(unsigned short)o[2] | ((unsigned int)(unsigned short)o[3] << 16)};
      asm volatile("global_store_dwordx2 %0, %1, off sc0 sc1"
                   :: "v"(p), "v"(ov) : "memory");
    }

    asm volatile("s_waitcnt vmcnt(0)" ::: "memory");
    __syncthreads();
    if (tid == 0) atomicAdd(&flags[tc], 1u);
    return;
  }

  // ============ LSTM role (R6 body + chunk waits + 2-deep Xp prefetch) ============
  signed char* As = (signed char*)SH;  // uses first 8192 B

  const int v = tid >> 6;
  const int wg = (int)blockIdx.x, b0 = wg * 2;

  const int4v zacc = {0, 0, 0, 0};
  ((int4v*)As)[tid] = zacc;

  int4v w[4][2][4];
#pragma unroll
  for (int g = 0; g < 4; ++g)
#pragma unroll
    for (int p = 0; p < 2; ++p)
#pragma unroll
      for (int kt = 0; kt < 4; ++kt) {
        const int ntg = g * 16 + v * 2 + p;
        w[g][p][kt] = *(const int4v*)(wq + (size_t)(((ntg * 4 + kt) * 64 + lane)) * 16);
      }

  const int r = (lane >> 4) & 1;
  const int ph = lane >> 5;
  const int u = v * 32 + ph * 16 + (lane & 15);

  float dq0 = dq[u], dq1 = dq[256 + u], dq2 = dq[512 + u], dq3 = dq[768 + u];
  const int lenm = lens[b0 + r] - 1;
  float c = 0.f, ckeep = 0.f, hkeep = 0.f;

  const signed char* AsR = As + lane * 16;
  signed char* AsW = As + ((u >> 6) * 1024 + (((u >> 4) & 3) * 16 + r * 4) * 16 + (u & 15));

  const char* xpb = (const char*)xp;
  unsigned int xoff = ((unsigned int)(b0 + r) * 1024u + (unsigned int)u * 4u) * 2u;
  char* outb = (char*)(out + 32768);
  unsigned int ooff = ((unsigned int)(b0 + r) * 524288u + (unsigned int)u) * 4u;

  // wait for xp t-chunk 0 (acquire -> inv stale lines)
  if (tid == 0) {
    while (__hip_atomic_load(&flags[0], __ATOMIC_ACQUIRE, __HIP_MEMORY_SCOPE_AGENT) < 512u)
      __builtin_amdgcn_s_sleep(8);
  }
  __syncthreads();

  // 2-deep prefetch queue: xcur = Xp[t], xnxt = Xp[t+1]
  uint2 xcur = *(const uint2*)(xpb + xoff);
  xoff += 131072u;
  uint2 xnxt = *(const uint2*)(xpb + xoff);
  xoff += 131072u;

  __syncthreads();

#define GATES(XPAIR, WOFF0, WOFF1)                                              \
  {                                                                             \
    const float xi = __uint_as_float(XPAIR.x << 16);                            \
    const float xf = __uint_as_float(XPAIR.x & 0xffff0000u);                    \
    const float xg = __uint_as_float(XPAIR.y << 16);                            \
    const float xo = __uint_as_float(XPAIR.y & 0xffff0000u);                    \
    const int ai = ph ? acc[0][1][0] : acc[0][0][0];                            \
    const int af_ = ph ? acc[1][1][0] : acc[1][0][0];                           \
    const int ag = ph ? acc[2][1][0] : acc[2][0][0];                            \
    const int ao = ph ? acc[3][1][0] : acc[3][0][0];                            \
    const float zi = fminf(fmaf((float)ai, dq0, xi), 28.85f);                   \
    const float zf = fmaf((float)af_, dq1, xf);                                 \
    const float zg = fminf(fmaf((float)ag, dq2, xg), 57.71f);                   \
    const float zo = fminf(fmaf((float)ao, dq3, xo), 28.85f);                   \
    const float ei = fexp2(zi);                                                 \
    const float e2g = fexp2(zg);                                                \
    const float ef = fexp2(zf);                                                 \
    const float eo = fexp2(zo);                                                 \
    const float p1 = ei * (e2g - 1.f) * frcp((ei + 1.f) * (e2g + 1.f));         \
    const float cn = fmaf(frcp(1.f + ef), c, p1);                               \
    c = cn;                                                                     \
    const float e2c = fexp2(fminf(cn, 15.f) * (2.f * LOG2E));                   \
    const float h = eo * (e2c - 1.f) * frcp((eo + 1.f) * (e2c + 1.f));          \
    const float hm = fmaf(h, 127.f, 12582912.f);                                \
    AsW[WOFF0] = (signed char)__float_as_uint(hm);                              \
    AsW[WOFF1] = (signed char)__float_as_uint(hm);                              \
    *(float*)(outb + ooff) = h;                                                 \
    ooff += 1024u;                                                              \
    if (t_ == lenm) { ckeep = cn; hkeep = h; }                                  \
  }

#define MFMA_BLOCK(O0, O1, O2, O3)                                              \
  int4v acc[4][2];                                                              \
  {                                                                             \
    const int4v a0 = *(const int4v*)(AsR + (O0));                               \
    const int4v a1 = *(const int4v*)(AsR + (O1));                               \
    const int4v a2 = *(const int4v*)(AsR + (O2));                               \
    const int4v a3 = *(const int4v*)(AsR + (O3));                               \
    _Pragma("unroll") for (int g = 0; g < 4; ++g)                               \
    _Pragma("unroll") for (int p = 0; p < 2; ++p) {                             \
      acc[g][p] = __builtin_amdgcn_mfma_i32_16x16x64_i8(a0, w[g][p][0], zacc, 0, 0, 0); \
      acc[g][p] = __builtin_amdgcn_mfma_i32_16x16x64_i8(a1, w[g][p][1], acc[g][p], 0, 0, 0); \
      acc[g][p] = __builtin_amdgcn_mfma_i32_16x16x64_i8(a2, w[g][p][2], acc[g][p], 0, 0, 0); \
      acc[g][p] = __builtin_amdgcn_mfma_i32_16x16x64_i8(a3, w[g][p][3], acc[g][p], 0, 0, 0); \
    }                                                                           \
  }

#pragma unroll 1
  for (int it = 0; it < 1024; ++it) {
    if ((it & 63) == 0) {
      const int ch0 = (it >> 6) + 1;
      const int ch = ch0 < 15 ? ch0 : 15;
      if (tid == 0) {
        while (__hip_atomic_load(&flags[ch], __ATOMIC_ACQUIRE, __HIP_MEMORY_SCOPE_AGENT) < 512u)
          __builtin_amdgcn_s_sleep(8);
      }
      __syncthreads();
    }
    {  // even t = 2*it: read buf0, write buf1
      const int t_ = 2 * it;
      const uint2 xpre = *(const uint2*)(xpb + xoff);  // Xp[t+2]
      xoff += 131072u;
      MFMA_BLOCK(0, 1024, 2048, 3072)
      GATES(xcur, 4096, 4224)
      xcur = xnxt;
      xnxt = xpre;
      __syncthreads();
    }
    {  // odd t = 2*it+1: read buf1, write buf0
      const int t_ = 2 * it + 1;
      const uint2 xpre = *(const uint2*)(xpb + xoff);  // Xp[t+3]
      xoff += 131072u;
      MFMA_BLOCK(4096, 5120, 6144, 7168)
      GATES(xcur, 0, 128)
      xcur = xnxt;
      xnxt = xpre;
      __syncthreads();
    }
  }
#undef GATES
#undef MFMA_BLOCK

  out[(size_t)(b0 + r) * 256 + u] = ckeep;
  out[16384 + (size_t)(b0 + r) * 256 + u] = hkeep;
}

// ---------------------------------------------------------------------------
extern "C" void kernel_launch(void* const* d_in, const int* in_sizes, int n_in,
                              void* d_out, int out_size, void* d_ws, size_t ws_size,
                              hipStream_t stream) {
  (void)in_sizes; (void)n_in; (void)out_size; (void)ws_size;
  const float* x = (const float*)d_in[0];
  const float* wi = (const float*)d_in[1];
  const float* wh = (const float*)d_in[2];
  const float* bias = (const float*)d_in[3];
  const int* lens = (const int*)d_in[4];
  float* out = (float*)d_out;

  char* ws = (char*)d_ws;
  unsigned short* xd = (unsigned short*)ws;                         // 64 MiB
  unsigned short* xp = (unsigned short*)(ws + 67108864ull);         // 256 MiB
  unsigned short* wit = (unsigned short*)(ws + 335544320ull);       // 512 KiB
  float* dq = (float*)(ws + 336068608ull);                          // 4 KiB
  float* qs = (float*)(ws + 336072704ull);                          // 4 KiB
  signed char* wqb = (signed char*)(ws + 336076800ull);             // 256 KiB
  unsigned int* flags = (unsigned int*)(ws + 336338944ull);         // 128 B

  hipMemsetAsync(flags, 0, 128, stream);
  k_prep<<<320, 256, 0, stream>>>(wi, wh, wit, dq, qs);
  k_pack_wh_i8<<<1024, 256, 0, stream>>>(wh, qs, wqb);
  k_fused<<<16416, 512, 0, stream>>>(x, xd, wit, bias, xp, wqb, dq, lens, out, flags);
}

// Round 15
// 1499.229 us; speedup vs baseline: 1.1552x; 1.1552x over previous
//
#include <hip/hip_runtime.h>

// ============================================================================
// UnidirecLSTMLayerWithDropoutBefore: dropout(Threefry) -> x@Wi GEMM -> LSTM
// B=64, T=2048, D=256, H=256, gates (i,f,g,o), dropout 0.1, key 42.
//
// R14 = R12 (best: 1506us) + k_prep merge (pack_wi+colscale in one launch).
// R13's in-kernel dropout pipeline REVERTED (sc0sc1 xd writes bypassed L2 ->
// gemm A-re-reads from MALL; 8192 tiny blocks' handshake overhead; 1506->1732).
//
// Structure: k_prep -> k_pack_wh_i8 -> k_dropout -> k_fused.
// k_fused: blocks [0,32) = lstm (R6 body, 83% of matrix-pipe floor);
//          blocks [32,8224) = gemm, t-chunk-major, sc0sc1 xp stores +
//          vmcnt(0) + one relaxed atomicAdd per block (validated R10);
//          lstm acquire-polls flags[chunk] one chunk ahead.
// 88KB LDS -> 1 block/CU: gemm never co-resides with an lstm block.
//
// ws layout (bytes):
//   [0, 64MiB)            Xd   bf16 [131072][256]
//   [64MiB, 320MiB)       Xp   bf16 [t*64+b][u*4+g], PRE-SCALED by gate:
//                              i,o: *L   f: *-L   g: *2L   (L = log2e)
//   [335544320, +512KiB)  WiT  bf16 [1024][256]
//   [336068608, +4KiB)    dq   f32 [1024]  (s/127^2 * gate-scale)
//   [336072704, +4KiB)    qs   f32 [1024]  (127/s)
//   [336076800, +256KiB)  Wq   i8 packed MFMA-B frags [ntg][kt][lane][16]
//   [336338944, +64B)     flags u32[16] (memsetAsync'd 0 each launch)
// Output f32: c_last[16384] | h_last[16384] | outputs[64*2048*256]
// ============================================================================

typedef __attribute__((ext_vector_type(8))) short short8;
typedef __attribute__((ext_vector_type(4))) float floatx4;
typedef __attribute__((ext_vector_type(4))) int int4v;
typedef __attribute__((ext_vector_type(4))) unsigned short us4;
typedef __attribute__((ext_vector_type(2))) unsigned int uint2v;

#define LOG2E 1.44269504088896f

__device__ __forceinline__ unsigned short f2bf(float f) {
  unsigned int u = __float_as_uint(f);
  u = u + 0x7fffu + ((u >> 16) & 1u);   // RNE
  return (unsigned short)(u >> 16);
}
__device__ __forceinline__ float fexp2(float x) { return __builtin_amdgcn_exp2f(x); }
__device__ __forceinline__ float frcp(float x) { return __builtin_amdgcn_rcpf(x); }

// ---------------------------------------------------------------------------
// Threefry-2x32, key (0,42), partitionable scheme (verified bit-exact R0-R13)
// ---------------------------------------------------------------------------
__device__ __forceinline__ unsigned int tf_bits(unsigned int x0, unsigned int x1) {
  const unsigned int K0 = 0u, K1 = 42u;
  const unsigned int KX = K0 ^ K1 ^ 0x1BD11BDAu;
  x0 += K0; x1 += K1;
#define TF_R(r) { x0 += x1; x1 = (x1 << (r)) | (x1 >> (32 - (r))); x1 ^= x0; }
  TF_R(13) TF_R(15) TF_R(26) TF_R(6)   x0 += K1; x1 += KX + 1u;
  TF_R(17) TF_R(29) TF_R(16) TF_R(24)  x0 += KX; x1 += K0 + 2u;
  TF_R(13) TF_R(15) TF_R(26) TF_R(6)   x0 += K0; x1 += K1 + 3u;
  TF_R(17) TF_R(29) TF_R(16) TF_R(24)  x0 += K1; x1 += KX + 4u;
  TF_R(13) TF_R(15) TF_R(26) TF_R(6)   x0 += KX; x1 += K0 + 5u;
#undef TF_R
  return x0 ^ x1;
}

__global__ __launch_bounds__(256) void k_dropout(const float* __restrict__ x,
                                                 unsigned short* __restrict__ xd) {
  const unsigned int base = (blockIdx.x * 256u + threadIdx.x) * 4u;
  const float4 xv = *reinterpret_cast<const float4*>(x + base);
  const float xs[4] = {xv.x, xv.y, xv.z, xv.w};
  us4 o;
#pragma unroll
  for (int j = 0; j < 4; ++j) {
    const unsigned int bits = tf_bits(0u, base + (unsigned int)j);
    const float u = __uint_as_float((bits >> 9) | 0x3f800000u) - 1.0f;
    const float v = (u < 0.9f) ? (xs[j] / 0.9f) : 0.0f;
    o[j] = f2bf(v);
  }
  *reinterpret_cast<us4*>(xd + base) = o;
}

// ---------------------------------------------------------------------------
// k_prep: blocks [0,64) = colscale role; blocks [64,320) = pack_wi role.
// ---------------------------------------------------------------------------
__global__ __launch_bounds__(256) void k_prep(const float* __restrict__ wi,
                                              const float* __restrict__ wh,
                                              unsigned short* __restrict__ wit,
                                              float* __restrict__ dq,
                                              float* __restrict__ qs) {
  if (blockIdx.x < 64) {
    __shared__ float red[256];
    const int t = threadIdx.x;
    const int n = blockIdx.x * 16 + (t & 15);
    const int kg = t >> 4;
    float m = 0.f;
#pragma unroll
    for (int i = 0; i < 16; ++i)
      m = fmaxf(m, fabsf(wh[(kg * 16 + i) * 1024 + n]));
    red[t] = m;
    __syncthreads();
    if (t < 16) {
      const int nn = blockIdx.x * 16 + t;
      float mm = red[t];
#pragma unroll
      for (int j = 1; j < 16; ++j) mm = fmaxf(mm, red[t + j * 16]);
      const float s = (mm > 0.f) ? mm : 1.f;
      const float gsc[4] = {LOG2E, -LOG2E, 2.f * LOG2E, LOG2E};
      dq[nn] = (s / 16129.0f) * gsc[nn >> 8];
      qs[nn] = 127.0f / s;
    }
    return;
  }
  // pack_wi: LDS-transpose, wit[n][k] = bf16(wi[k][n])
  __shared__ float tile[32][33];
  const int idx = (int)blockIdx.x - 64;      // 0..255
  const int k0 = (idx & 7) * 32, n0 = (idx >> 3) * 32;
  const int tx = threadIdx.x & 31, ty = threadIdx.x >> 5;
#pragma unroll
  for (int i = 0; i < 4; ++i)
    tile[ty + i * 8][tx] = wi[(k0 + ty + i * 8) * 1024 + n0 + tx];
  __syncthreads();
#pragma unroll
  for (int i = 0; i < 4; ++i)
    wit[(n0 + ty + i * 8) * 256 + k0 + tx] = f2bf(tile[tx][ty + i * 8]);
}

// Wq packed in i8 MFMA-B fragment order (16x16x64) — layout validated R1-R13.
__global__ __launch_bounds__(256) void k_pack_wh_i8(const float* __restrict__ wh,
                                                    const float* __restrict__ qs,
                                                    signed char* __restrict__ wq) {
  const int tid = blockIdx.x * 256 + threadIdx.x;
  const int j = tid & 15, l = (tid >> 4) & 63, kt = (tid >> 10) & 3, ntg = tid >> 12;
  const int k = kt * 64 + ((l >> 4) << 4) + j;
  const int n = ntg * 16 + (l & 15);
  float v = rintf(wh[k * 1024 + n] * qs[n]);
  v = fminf(fmaxf(v, -127.f), 127.f);
  wq[tid] = (signed char)(int)v;
}

// ---------------------------------------------------------------------------
// FUSED kernel: blocks 0..31 lstm, 32..8223 gemm (t-chunk-major order).
// ---------------------------------------------------------------------------
__global__ __launch_bounds__(512, 2) void k_fused(
    const unsigned short* __restrict__ xd, const unsigned short* __restrict__ wit,
    const float* __restrict__ bias, unsigned short* __restrict__ xp,
    const signed char* __restrict__ wq, const float* __restrict__ dq,
    const int* __restrict__ lens, float* __restrict__ out,
    unsigned int* __restrict__ flags) {
  __shared__ __align__(16) unsigned short SH[45056];  // 88 KB -> 1 block/CU

  const int tid = threadIdx.x, lane = tid & 63;

  if (blockIdx.x >= 32) {
    // ======================= GEMM role =======================
    const int gb = (int)blockIdx.x - 32;
    const int tc = gb >> 9;
    const int rem = gb & 511;
    const int b = rem >> 3, y = rem & 7;
    const int m0 = b * 2048 + tc * 128;

    const int wv = tid >> 6;
    const int wm = wv >> 2;
    const int wn = wv & 3;
    const int srow = tid >> 2, sseg = tid & 3;
    const unsigned short* gA = xd + (m0 + srow) * 256 + sseg * 8;
    const int nsrc = ((srow >> 5) << 8) + y * 32 + (srow & 31);
    const unsigned short* gB = wit + nsrc * 256 + sseg * 8;
    const int soff = srow * 40 + sseg * 8;

    const floatx4 zero4 = {0.f, 0.f, 0.f, 0.f};
    floatx4 acc[4][2];
#pragma unroll
    for (int i = 0; i < 4; ++i) { acc[i][0] = zero4; acc[i][1] = zero4; }

    short8 ra = *(const short8*)(gA);
    short8 rb = *(const short8*)(gB);
    *(short8*)&SH[soff] = ra;
    *(short8*)&SH[10240 + soff] = rb;
    __syncthreads();

    const int frow = (lane & 15) * 40 + ((lane >> 4) << 3);
#pragma unroll 1
    for (int kt = 0; kt < 8; ++kt) {
      const int boff = (kt & 1) * 5120;
      if (kt < 7) {
        ra = *(const short8*)(gA + (kt + 1) * 32);
        rb = *(const short8*)(gB + (kt + 1) * 32);
      }
      short8 af[4], bfv[2];
#pragma unroll
      for (int mt = 0; mt < 4; ++mt)
        af[mt] = *(const short8*)&SH[boff + (wm * 64 + mt * 16) * 40 + frow];
#pragma unroll
      for (int nt = 0; nt < 2; ++nt)
        bfv[nt] = *(const short8*)&SH[10240 + boff + (wn * 32 + nt * 16) * 40 + frow];
#pragma unroll
      for (int mt = 0; mt < 4; ++mt)
#pragma unroll
        for (int nt = 0; nt < 2; ++nt)
          acc[mt][nt] = __builtin_amdgcn_mfma_f32_16x16x32_bf16(af[mt], bfv[nt], acc[mt][nt], 0, 0, 0);
      if (kt < 7) {
        const int noff = boff ^ 5120;
        *(short8*)&SH[noff + soff] = ra;
        *(short8*)&SH[10240 + noff + soff] = rb;
      }
      __syncthreads();
    }

    const float gsc[4] = {LOG2E, -LOG2E, 2.f * LOG2E, LOG2E};
    const float gv = gsc[wn];
    float bv[2];
#pragma unroll
    for (int nt = 0; nt < 2; ++nt)
      bv[nt] = bias[wn * 256 + y * 32 + nt * 16 + (lane & 15)];

    __syncthreads();
#pragma unroll
    for (int mt = 0; mt < 4; ++mt)
#pragma unroll
      for (int nt = 0; nt < 2; ++nt) {
        const int jj = wn * 32 + nt * 16 + (lane & 15);
#pragma unroll
        for (int q = 0; q < 4; ++q) {
          const int row = wm * 64 + mt * 16 + ((lane >> 4) << 2) + q;
          SH[row * 132 + jj] = f2bf((acc[mt][nt][q] + bv[nt]) * gv);
        }
      }
    __syncthreads();

    // xp stores: sc0 sc1 write-through (no dirty L2 -> no fence needed).
#pragma unroll
    for (int k = 0; k < 8; ++k) {
      const int pi = k * 512 + tid;
      const int row = pi >> 5, u = pi & 31;
      us4 o = {SH[row * 132 + u], SH[row * 132 + 32 + u],
               SH[row * 132 + 64 + u], SH[row * 132 + 96 + u]};
      const int m = m0 + row;
      unsigned short* p = xp + ((size_t)(m & 2047) * 64 + (m >> 11)) * 1024 +
                          (size_t)(y * 32 + u) * 4;
      const uint2v ov = {(unsigned int)(unsigned short)o[0] | ((unsigned int)(unsigned short)o[1] << 16),
                         (unsigned int)(unsigned short)o[2] | ((unsigned int)(unsigned short)o[3] << 16)};
      asm volatile("global_store_dwordx2 %0, %1, off sc0 sc1"
                   :: "v"(p), "v"(ov) : "memory");
    }

    asm volatile("s_waitcnt vmcnt(0)" ::: "memory");  // stores at coherence pt
    __syncthreads();
    if (tid == 0) atomicAdd(&flags[tc], 1u);          // relaxed device-scope
    return;
  }

  // ============ LSTM role (R6 body + chunk waits + 2-deep Xp prefetch) ============
  signed char* As = (signed char*)SH;  // uses first 8192 B

  const int v = tid >> 6;
  const int wg = (int)blockIdx.x, b0 = wg * 2;

  const int4v zacc = {0, 0, 0, 0};
  ((int4v*)As)[tid] = zacc;

  int4v w[4][2][4];
#pragma unroll
  for (int g = 0; g < 4; ++g)
#pragma unroll
    for (int p = 0; p < 2; ++p)
#pragma unroll
      for (int kt = 0; kt < 4; ++kt) {
        const int ntg = g * 16 + v * 2 + p;
        w[g][p][kt] = *(const int4v*)(wq + (size_t)(((ntg * 4 + kt) * 64 + lane)) * 16);
      }

  const int r = (lane >> 4) & 1;
  const int ph = lane >> 5;
  const int u = v * 32 + ph * 16 + (lane & 15);

  float dq0 = dq[u], dq1 = dq[256 + u], dq2 = dq[512 + u], dq3 = dq[768 + u];
  const int lenm = lens[b0 + r] - 1;
  float c = 0.f, ckeep = 0.f, hkeep = 0.f;

  const signed char* AsR = As + lane * 16;
  signed char* AsW = As + ((u >> 6) * 1024 + (((u >> 4) & 3) * 16 + r * 4) * 16 + (u & 15));

  const char* xpb = (const char*)xp;
  unsigned int xoff = ((unsigned int)(b0 + r) * 1024u + (unsigned int)u * 4u) * 2u;
  char* outb = (char*)(out + 32768);
  unsigned int ooff = ((unsigned int)(b0 + r) * 524288u + (unsigned int)u) * 4u;

  // wait for xp t-chunk 0 (acquire -> inv stale lines)
  if (tid == 0) {
    while (__hip_atomic_load(&flags[0], __ATOMIC_ACQUIRE, __HIP_MEMORY_SCOPE_AGENT) < 512u)
      __builtin_amdgcn_s_sleep(8);
  }
  __syncthreads();

  // 2-deep prefetch queue: xcur = Xp[t], xnxt = Xp[t+1]
  uint2 xcur = *(const uint2*)(xpb + xoff);
  xoff += 131072u;
  uint2 xnxt = *(const uint2*)(xpb + xoff);
  xoff += 131072u;

  __syncthreads();

#define GATES(XPAIR, WOFF0, WOFF1)                                              \
  {                                                                             \
    const float xi = __uint_as_float(XPAIR.x << 16);                            \
    const float xf = __uint_as_float(XPAIR.x & 0xffff0000u);                    \
    const float xg = __uint_as_float(XPAIR.y << 16);                            \
    const float xo = __uint_as_float(XPAIR.y & 0xffff0000u);                    \
    const int ai = ph ? acc[0][1][0] : acc[0][0][0];                            \
    const int af_ = ph ? acc[1][1][0] : acc[1][0][0];                           \
    const int ag = ph ? acc[2][1][0] : acc[2][0][0];                            \
    const int ao = ph ? acc[3][1][0] : acc[3][0][0];                            \
    const float zi = fminf(fmaf((float)ai, dq0, xi), 28.85f);                   \
    const float zf = fmaf((float)af_, dq1, xf);                                 \
    const float zg = fminf(fmaf((float)ag, dq2, xg), 57.71f);                   \
    const float zo = fminf(fmaf((float)ao, dq3, xo), 28.85f);                   \
    const float ei = fexp2(zi);                                                 \
    const float e2g = fexp2(zg);                                                \
    const float ef = fexp2(zf);                                                 \
    const float eo = fexp2(zo);                                                 \
    const float p1 = ei * (e2g - 1.f) * frcp((ei + 1.f) * (e2g + 1.f));         \
    const float cn = fmaf(frcp(1.f + ef), c, p1);                               \
    c = cn;                                                                     \
    const float e2c = fexp2(fminf(cn, 15.f) * (2.f * LOG2E));                   \
    const float h = eo * (e2c - 1.f) * frcp((eo + 1.f) * (e2c + 1.f));          \
    const float hm = fmaf(h, 127.f, 12582912.f);                                \
    AsW[WOFF0] = (signed char)__float_as_uint(hm);                              \
    AsW[WOFF1] = (signed char)__float_as_uint(hm);                              \
    *(float*)(outb + ooff) = h;                                                 \
    ooff += 1024u;                                                              \
    if (t_ == lenm) { ckeep = cn; hkeep = h; }                                  \
  }

#define MFMA_BLOCK(O0, O1, O2, O3)                                              \
  int4v acc[4][2];                                                              \
  {                                                                             \
    const int4v a0 = *(const int4v*)(AsR + (O0));                               \
    const int4v a1 = *(const int4v*)(AsR + (O1));                               \
    const int4v a2 = *(const int4v*)(AsR + (O2));                               \
    const int4v a3 = *(const int4v*)(AsR + (O3));                               \
    _Pragma("unroll") for (int g = 0; g < 4; ++g)                               \
    _Pragma("unroll") for (int p = 0; p < 2; ++p) {                             \
      acc[g][p] = __builtin_amdgcn_mfma_i32_16x16x64_i8(a0, w[g][p][0], zacc, 0, 0, 0); \
      acc[g][p] = __builtin_amdgcn_mfma_i32_16x16x64_i8(a1, w[g][p][1], acc[g][p], 0, 0, 0); \
      acc[g][p] = __builtin_amdgcn_mfma_i32_16x16x64_i8(a2, w[g][p][2], acc[g][p], 0, 0, 0); \
      acc[g][p] = __builtin_amdgcn_mfma_i32_16x16x64_i8(a3, w[g][p][3], acc[g][p], 0, 0, 0); \
    }                                                                           \
  }

#pragma unroll 1
  for (int it = 0; it < 1024; ++it) {
    if ((it & 63) == 0) {
      const int ch0 = (it >> 6) + 1;
      const int ch = ch0 < 15 ? ch0 : 15;
      if (tid == 0) {
        while (__hip_atomic_load(&flags[ch], __ATOMIC_ACQUIRE, __HIP_MEMORY_SCOPE_AGENT) < 512u)
          __builtin_amdgcn_s_sleep(8);
      }
      __syncthreads();
    }
    {  // even t = 2*it: read buf0, write buf1
      const int t_ = 2 * it;
      const uint2 xpre = *(const uint2*)(xpb + xoff);  // Xp[t+2]
      xoff += 131072u;
      MFMA_BLOCK(0, 1024, 2048, 3072)
      GATES(xcur, 4096, 4224)
      xcur = xnxt;
      xnxt = xpre;
      __syncthreads();
    }
    {  // odd t = 2*it+1: read buf1, write buf0
      const int t_ = 2 * it + 1;
      const uint2 xpre = *(const uint2*)(xpb + xoff);  // Xp[t+3]
      xoff += 131072u;
      MFMA_BLOCK(4096, 5120, 6144, 7168)
      GATES(xcur, 0, 128)
      xcur = xnxt;
      xnxt = xpre;
      __syncthreads();
    }
  }
#undef GATES
#undef MFMA_BLOCK

  out[(size_t)(b0 + r) * 256 + u] = ckeep;
  out[16384 + (size_t)(b0 + r) * 256 + u] = hkeep;
}

// ---------------------------------------------------------------------------
extern "C" void kernel_launch(void* const* d_in, const int* in_sizes, int n_in,
                              void* d_out, int out_size, void* d_ws, size_t ws_size,
                              hipStream_t stream) {
  (void)in_sizes; (void)n_in; (void)out_size; (void)ws_size;
  const float* x = (const float*)d_in[0];
  const float* wi = (const float*)d_in[1];
  const float* wh = (const float*)d_in[2];
  const float* bias = (const float*)d_in[3];
  const int* lens = (const int*)d_in[4];
  float* out = (float*)d_out;

  char* ws = (char*)d_ws;
  unsigned short* xd = (unsigned short*)ws;                         // 64 MiB
  unsigned short* xp = (unsigned short*)(ws + 67108864ull);         // 256 MiB
  unsigned short* wit = (unsigned short*)(ws + 335544320ull);       // 512 KiB
  float* dq = (float*)(ws + 336068608ull);                          // 4 KiB
  float* qs = (float*)(ws + 336072704ull);                          // 4 KiB
  signed char* wqb = (signed char*)(ws + 336076800ull);             // 256 KiB
  unsigned int* flags = (unsigned int*)(ws + 336338944ull);         // 64 B

  hipMemsetAsync(flags, 0, 64, stream);
  k_prep<<<320, 256, 0, stream>>>(wi, wh, wit, dq, qs);
  k_pack_wh_i8<<<1024, 256, 0, stream>>>(wh, qs, wqb);
  k_dropout<<<32768, 256, 0, stream>>>(x, xd);
  k_fused<<<8224, 512, 0, stream>>>(xd, wit, bias, xp, wqb, dq, lens, out, flags);
}